// Round 8
// baseline (352.947 us; speedup 1.0000x reference)
//
#include <hip/hip_runtime.h>
#include <hip/hip_bf16.h>

#define N_NODES 100000
#define N_EDGES 600000
#define D_IN 128
#define D_OUT 512
#define CAP 40        // bucket capacity per node (Poisson(6): P(deg>=40) ~ 1e-20)
#define OVF_CAP 1024

typedef __bf16 bf16x8 __attribute__((ext_vector_type(8)));
typedef __bf16 bf16x2 __attribute__((ext_vector_type(2)));
typedef float f32x4 __attribute__((ext_vector_type(4)));

// ---- workspace layout (bytes) ----
// (h region retired; kept offsets stable)
// cnt    : [25,600,000, 26,000,000)       N_NODES*4
// ovf_cnt: [26,000,000, 26,000,016)       (memset covers cnt+ovf_cnt in one go)
// ovf    : [26,000,016, 26,008,208)       OVF_CAP * int2
// bucket : [26,008,208, 42,008,208)       N_NODES*CAP*4
// xb     : [42,008,208, 67,608,208)       N_NODES*128*2   (x in bf16, gather table)
// wb     : [67,608,208, 67,739,280)       512*128*2       (W in bf16)
#define OFF_CNT   25600000
#define OFF_OVFC  26000000
#define OFF_OVF   26000016
#define OFF_BUCK  26008208
#define OFF_XB    42008208
#define OFF_WB    67608208

__device__ inline bf16x8 cvt8(float4 v0, float4 v1) {
    bf16x8 u = { (__bf16)v0.x, (__bf16)v0.y, (__bf16)v0.z, (__bf16)v0.w,
                 (__bf16)v1.x, (__bf16)v1.y, (__bf16)v1.z, (__bf16)v1.w };
    return u;
}

__device__ inline float blo(unsigned int u) { return __uint_as_float(u << 16); }
__device__ inline float bhi(unsigned int u) { return __uint_as_float(u & 0xffff0000u); }

// ---------------- kernel 1: buckets + x->bf16 + W->bf16 (fused) -------------
#define EB  2344   // ceil(600000/256)
#define XB  6250   // 100000*128 / 2048
#define WBK 32     // 512*128 / 2048
__global__ void k_bucket_cvt(const int* __restrict__ ei, const float* __restrict__ x,
                             const float* __restrict__ W, int* __restrict__ cnt,
                             int* __restrict__ bucket, int* __restrict__ ovf_cnt,
                             int2* __restrict__ ovf, __bf16* __restrict__ xb,
                             __bf16* __restrict__ wb) {
    int b = blockIdx.x;
    if (b < EB) {
        int e = b * 256 + threadIdx.x;
        if (e >= N_EDGES) return;
        int r = ei[e];            // destination
        int c = ei[N_EDGES + e];  // source
        int slot = atomicAdd(&cnt[r], 1);
        if (slot < CAP) {
            bucket[(size_t)r * CAP + slot] = c;
        } else {
            int oi = atomicAdd(ovf_cnt, 1);
            if (oi < OVF_CAP) ovf[oi] = make_int2(r, c);
        }
    } else if (b < EB + XB) {
        size_t i = (size_t)(b - EB) * 2048 + threadIdx.x * 8;
        float4 v0 = *(const float4*)(x + i);
        float4 v1 = *(const float4*)(x + i + 4);
        *(bf16x8*)(xb + i) = cvt8(v0, v1);
    } else {
        size_t i = (size_t)(b - EB - XB) * 2048 + threadIdx.x * 8;
        float4 v0 = *(const float4*)(W + i);
        float4 v1 = *(const float4*)(W + i + 4);
        *(bf16x8*)(wb + i) = cvt8(v0, v1);
    }
}

// ---------------- kernel 2: FUSED agg + GEMM --------------------------------
// One block = one 128-node m-panel. Phase 1: aggregate h-rows straight into
// the LDS A-tile (no global h). 8 passes x (2 nodes per wave), 2-stage
// software pipeline (pass p+1 front loads issued before processing pass p),
// 8 outstanding gathers per wave. Phase 2: 4 n-quarters of W (128 cols each)
// staged to LDS from the L2-resident bf16 wb, MFMA, NT-store.
// LDS = 2 x 34816 B = 70KB -> 2 blocks/CU (16 waves/CU keeps gather TLP;
// one block's agg overlaps the co-resident block's MFMA).
#define BM 128
#define LDA 136   // +8 pad: row stride 272B -> 2-way bank alias (free per m136)
#define LDB 136
#define NBLK 782  // ceil(100000/128)

__launch_bounds__(512, 4)
__global__ void k_fused(const float* __restrict__ x, const __bf16* __restrict__ xb,
                        const __bf16* __restrict__ wb, const int* __restrict__ cnt,
                        const int* __restrict__ bucket, const int* __restrict__ ovf_cnt,
                        const int2* __restrict__ ovf, const float* __restrict__ bias,
                        float* __restrict__ out) {
    __shared__ __bf16 As[BM * LDA];   // 34816 B
    __shared__ __bf16 Bs[128 * LDB];  // 34816 B

    int tid  = threadIdx.x;
    int lane = tid & 63;
    int wave = tid >> 6;   // 0..7
    int m0   = blockIdx.x * BM;
    const unsigned int* xbu = (const unsigned int*)xb;

    // ---------------- phase 1: aggregation into As ----------------
    auto loadp = [&](int p, int& mA, int& mB, unsigned int& rA, unsigned int& rB,
                     int& cA, int& cB) {
        int iA = p * 16 + wave * 2;
        int gA = m0 + iA;     if (gA > N_NODES - 1) gA = N_NODES - 1;
        int gB = m0 + iA + 1; if (gB > N_NODES - 1) gB = N_NODES - 1;
        mA = (lane < CAP) ? bucket[(size_t)gA * CAP + lane] : 0;
        mB = (lane < CAP) ? bucket[(size_t)gB * CAP + lane] : 0;
        rA = xbu[(size_t)gA * 64 + lane];
        rB = xbu[(size_t)gB * 64 + lane];
        cA = cnt[gA];
        cB = cnt[gB];
    };

    int pmA, pmB, pcA, pcB;
    unsigned int prA, prB;
    loadp(0, pmA, pmB, prA, prB, pcA, pcB);

    #pragma unroll
    for (int p = 0; p < 8; ++p) {
        int mA = pmA, mB = pmB, cA = pcA, cB = pcB;
        unsigned int rA = prA, rB = prB;
        if (p < 7) loadp(p + 1, pmA, pmB, prA, prB, pcA, pcB);  // issue-ahead

        int iA = p * 16 + wave * 2;
        int gA = m0 + iA;     if (gA > N_NODES - 1) gA = N_NODES - 1;
        int gB = m0 + iA + 1; if (gB > N_NODES - 1) gB = N_NODES - 1;

        int degA = __builtin_amdgcn_readfirstlane(cA);
        int degB = __builtin_amdgcn_readfirstlane(cB);
        int dA = degA < CAP ? degA : CAP;
        int dB = degB < CAP ? degB : CAP;
        int dmax = dA > dB ? dA : dB;

        float aX0 = blo(rA), aY0 = bhi(rA), aX1 = 0.f, aY1 = 0.f;
        float bX0 = blo(rB), bY0 = bhi(rB), bX1 = 0.f, bY1 = 0.f;

        for (int d = 0; d < dmax; d += 4) {  // 8 gathers in flight
            int cA0 = (d     < dA) ? __builtin_amdgcn_readlane(mA, d)     : 0;
            int cA1 = (d + 1 < dA) ? __builtin_amdgcn_readlane(mA, d + 1) : 0;
            int cA2 = (d + 2 < dA) ? __builtin_amdgcn_readlane(mA, d + 2) : 0;
            int cA3 = (d + 3 < dA) ? __builtin_amdgcn_readlane(mA, d + 3) : 0;
            int cB0 = (d     < dB) ? __builtin_amdgcn_readlane(mB, d)     : 0;
            int cB1 = (d + 1 < dB) ? __builtin_amdgcn_readlane(mB, d + 1) : 0;
            int cB2 = (d + 2 < dB) ? __builtin_amdgcn_readlane(mB, d + 2) : 0;
            int cB3 = (d + 3 < dB) ? __builtin_amdgcn_readlane(mB, d + 3) : 0;
            float sA0 = (d     < dA) ? 1.f : 0.f;
            float sA1 = (d + 1 < dA) ? 1.f : 0.f;
            float sA2 = (d + 2 < dA) ? 1.f : 0.f;
            float sA3 = (d + 3 < dA) ? 1.f : 0.f;
            float sB0 = (d     < dB) ? 1.f : 0.f;
            float sB1 = (d + 1 < dB) ? 1.f : 0.f;
            float sB2 = (d + 2 < dB) ? 1.f : 0.f;
            float sB3 = (d + 3 < dB) ? 1.f : 0.f;
            unsigned int uA0 = xbu[(size_t)cA0 * 64 + lane];
            unsigned int uA1 = xbu[(size_t)cA1 * 64 + lane];
            unsigned int uA2 = xbu[(size_t)cA2 * 64 + lane];
            unsigned int uA3 = xbu[(size_t)cA3 * 64 + lane];
            unsigned int uB0 = xbu[(size_t)cB0 * 64 + lane];
            unsigned int uB1 = xbu[(size_t)cB1 * 64 + lane];
            unsigned int uB2 = xbu[(size_t)cB2 * 64 + lane];
            unsigned int uB3 = xbu[(size_t)cB3 * 64 + lane];
            aX0 = fmaf(sA0, blo(uA0), aX0); aY0 = fmaf(sA0, bhi(uA0), aY0);
            aX1 = fmaf(sA1, blo(uA1), aX1); aY1 = fmaf(sA1, bhi(uA1), aY1);
            aX0 = fmaf(sA2, blo(uA2), aX0); aY0 = fmaf(sA2, bhi(uA2), aY0);
            aX1 = fmaf(sA3, blo(uA3), aX1); aY1 = fmaf(sA3, bhi(uA3), aY1);
            bX0 = fmaf(sB0, blo(uB0), bX0); bY0 = fmaf(sB0, bhi(uB0), bY0);
            bX1 = fmaf(sB1, blo(uB1), bX1); bY1 = fmaf(sB1, bhi(uB1), bY1);
            bX0 = fmaf(sB2, blo(uB2), bX0); bY0 = fmaf(sB2, bhi(uB2), bY0);
            bX1 = fmaf(sB3, blo(uB3), bX1); bY1 = fmaf(sB3, bhi(uB3), bY1);
        }
        aX0 += aX1; aY0 += aY1;
        bX0 += bX1; bY0 += bY1;

        if (degA > CAP || degB > CAP) {  // statistically never; correctness fallback
            const float2* xr = (const float2*)x;
            int n = *ovf_cnt;
            if (n > OVF_CAP) n = OVF_CAP;
            for (int i = 0; i < n; ++i) {
                int2 e = ovf[i];
                if (e.x == gA) {
                    float2 v = xr[(size_t)e.y * 64 + lane];
                    aX0 += v.x; aY0 += v.y;
                }
                if (e.x == gB) {
                    float2 v = xr[(size_t)e.y * 64 + lane];
                    bX0 += v.x; bY0 += v.y;
                }
            }
        }

        bf16x2 oA = { (__bf16)aX0, (__bf16)aY0 };
        bf16x2 oB = { (__bf16)bX0, (__bf16)bY0 };
        *(bf16x2*)&As[iA * LDA + 2 * lane] = oA;
        *(bf16x2*)&As[(iA + 1) * LDA + 2 * lane] = oB;
    }
    __syncthreads();

    // ---------------- phase 2: GEMM over 4 W-quarters ----------------
    int wm = wave & 1;     // 2 waves along m (64 rows each)
    int wn = wave >> 1;    // 4 waves along n (32 cols each)
    int quad = lane >> 4;
    int l16 = lane & 15;
    const __bf16* Abase = &As[(wm * 64 + l16) * LDA + quad * 8];
    const __bf16* Bbase = &Bs[(wn * 32 + l16) * LDB + quad * 8];

    #pragma unroll 1
    for (int nq = 0; nq < 4; ++nq) {
        if (nq) __syncthreads();  // Bs consumed by previous quarter's MFMA
        int n0 = nq * 128;
        #pragma unroll
        for (int it = 0; it < 4; ++it) {
            int i = tid + it * 512;
            int r = i >> 4;
            int c = (i & 15) << 3;
            *(bf16x8*)&Bs[r * LDB + c] =
                *(const bf16x8*)(wb + (size_t)(n0 + r) * D_IN + c);
        }
        __syncthreads();

        f32x4 acc[4][2] = {};
        #pragma unroll
        for (int ks = 0; ks < 4; ++ks) {
            bf16x8 a0 = *(const bf16x8*)(Abase + ks * 32);
            bf16x8 a1 = *(const bf16x8*)(Abase + 16 * LDA + ks * 32);
            bf16x8 a2 = *(const bf16x8*)(Abase + 32 * LDA + ks * 32);
            bf16x8 a3 = *(const bf16x8*)(Abase + 48 * LDA + ks * 32);
            bf16x8 b0 = *(const bf16x8*)(Bbase + ks * 32);
            bf16x8 b1 = *(const bf16x8*)(Bbase + 16 * LDB + ks * 32);
            acc[0][0] = __builtin_amdgcn_mfma_f32_16x16x32_bf16(a0, b0, acc[0][0], 0, 0, 0);
            acc[0][1] = __builtin_amdgcn_mfma_f32_16x16x32_bf16(a0, b1, acc[0][1], 0, 0, 0);
            acc[1][0] = __builtin_amdgcn_mfma_f32_16x16x32_bf16(a1, b0, acc[1][0], 0, 0, 0);
            acc[1][1] = __builtin_amdgcn_mfma_f32_16x16x32_bf16(a1, b1, acc[1][1], 0, 0, 0);
            acc[2][0] = __builtin_amdgcn_mfma_f32_16x16x32_bf16(a2, b0, acc[2][0], 0, 0, 0);
            acc[2][1] = __builtin_amdgcn_mfma_f32_16x16x32_bf16(a2, b1, acc[2][1], 0, 0, 0);
            acc[3][0] = __builtin_amdgcn_mfma_f32_16x16x32_bf16(a3, b0, acc[3][0], 0, 0, 0);
            acc[3][1] = __builtin_amdgcn_mfma_f32_16x16x32_bf16(a3, b1, acc[3][1], 0, 0, 0);
        }

        float bias0 = bias[n0 + wn * 32 + l16];
        float bias1 = bias[n0 + wn * 32 + 16 + l16];
        #pragma unroll
        for (int mt = 0; mt < 4; ++mt) {
            int mrow = m0 + wm * 64 + mt * 16 + quad * 4;
            #pragma unroll
            for (int nt = 0; nt < 2; ++nt) {
                int ncol = n0 + wn * 32 + nt * 16 + l16;
                float bv = nt ? bias1 : bias0;
                #pragma unroll
                for (int rg = 0; rg < 4; ++rg) {
                    int m = mrow + rg;
                    if (m < N_NODES)
                        __builtin_nontemporal_store(acc[mt][nt][rg] + bv,
                                                    &out[(size_t)m * D_OUT + ncol]);
                }
            }
        }
    }
}

extern "C" void kernel_launch(void* const* d_in, const int* in_sizes, int n_in,
                              void* d_out, int out_size, void* d_ws, size_t ws_size,
                              hipStream_t stream) {
    const float* x  = (const float*)d_in[0];
    const int*   ei = (const int*)d_in[1];
    const float* W  = (const float*)d_in[2];
    const float* b  = (const float*)d_in[3];
    float* out = (float*)d_out;

    char* ws = (char*)d_ws;
    int* cnt     = (int*)(ws + OFF_CNT);
    int* ovf_cnt = (int*)(ws + OFF_OVFC);
    int2* ovf    = (int2*)(ws + OFF_OVF);
    int* bucket  = (int*)(ws + OFF_BUCK);
    __bf16* xb   = (__bf16*)(ws + OFF_XB);
    __bf16* wb   = (__bf16*)(ws + OFF_WB);

    // zero cnt + ovf_cnt (contiguous region)
    hipMemsetAsync(cnt, 0, (OFF_OVFC - OFF_CNT) + 16, stream);

    k_bucket_cvt<<<EB + XB + WBK, 256, 0, stream>>>(ei, x, W, cnt, bucket,
                                                    ovf_cnt, ovf, xb, wb);
    k_fused<<<NBLK, 512, 0, stream>>>(x, xb, wb, cnt, bucket, ovf_cnt, ovf, b, out);
}